// Round 2
// baseline (49.621 us; speedup 1.0000x reference)
//
#include <hip/hip_runtime.h>
#include <math.h>

#define EPS_CLN 1e-6f

// Problem dims (fixed by the reference's setup_inputs)
constexpr int Bb = 8;
constexpr int Cc = 256;
constexpr int Tt = 8192;

// Tiling: one block = one b  x  TT consecutive t-values  x  all C channels.
// Thread = (channel-group cg of CPT channels) x (one float4 of t).
constexpr int TT   = 32;          // t-values per block
constexpr int CPT  = 8;           // channels per thread
constexpr int NCG  = Cc / CPT;    // 32 channel groups
constexpr int NT4  = TT / 4;      // 8 float4 slots along t
constexpr int NTHR = NCG * NT4;   // 256 threads
constexpr int NTB  = Tt / TT;     // 256 t-blocks per b

typedef float vfloat4 __attribute__((ext_vector_type(4)));

__global__ __launch_bounds__(NTHR, 4)
void cln_kernel(const float* __restrict__ xr_g, const float* __restrict__ xi_g,
                const float* __restrict__ wgt, const float* __restrict__ bs,
                float* __restrict__ yr_g, float* __restrict__ yi_g) {
    // Partial-sum scratch: [stat][channel-group][t]  (5*32*32*4 = 20 KB)
    __shared__ float red[5][NCG][TT];
    // Per-t params: raw sums -> then overwritten with mu_r, mu_i, W00, W01, W11
    __shared__ float wlds[5][TT];

    const int tid = threadIdx.x;
    const int t4i = tid & (NT4 - 1);   // which float4 along t
    const int cg  = tid >> 3;          // channel group (tid / NT4)
    const int tb  = blockIdx.x & (NTB - 1);
    const int b   = blockIdx.x >> 8;   // / NTB (=256)
    const int tl  = t4i * 4;           // local t of this thread's float4

    const int cbase = cg * CPT;
    const int base  = (b * Cc + cbase) * Tt + tb * TT + tl;

    // ---- single HBM read: 8 channels x 4 t x {re,im}, held in registers ----
    float4 xr[CPT], xi[CPT];
#pragma unroll
    for (int k = 0; k < CPT; ++k) {
        xr[k] = *(const float4*)(xr_g + base + k * Tt);
        xi[k] = *(const float4*)(xi_g + base + k * Tt);
    }

    // ---- per-thread partial stats over its 8 channels (componentwise per t) ----
    float4 sr = make_float4(0.f, 0.f, 0.f, 0.f);
    float4 si = sr, srr = sr, sri = sr, sii = sr;
#pragma unroll
    for (int k = 0; k < CPT; ++k) {
#define ACC1(c) { float r = xr[k].c, m = xi[k].c;          \
        sr.c += r; si.c += m;                              \
        srr.c = fmaf(r, r, srr.c);                         \
        sri.c = fmaf(r, m, sri.c);                         \
        sii.c = fmaf(m, m, sii.c); }
        ACC1(x) ACC1(y) ACC1(z) ACC1(w)
#undef ACC1
    }

    *(float4*)&red[0][cg][tl] = sr;
    *(float4*)&red[1][cg][tl] = si;
    *(float4*)&red[2][cg][tl] = srr;
    *(float4*)&red[3][cg][tl] = sri;
    *(float4*)&red[4][cg][tl] = sii;
    __syncthreads();

    // ---- parallel reduce over the 32 channel groups: 160 threads, one per (stat,t) ----
    if (tid < 5 * TT) {
        const int st = tid >> 5;       // stat 0..4
        const int t  = tid & (TT - 1); // t 0..31  -> bank = t, conflict-free
        float s = 0.f;
#pragma unroll
        for (int g = 0; g < NCG; ++g) s += red[st][g][t];
        wlds[st][t] = s;
    }
    __syncthreads();

    // ---- closed-form 2x2 inverse-sqrt whitening matrix, one thread per t ----
    if (tid < TT) {
        const float invC = 1.0f / (float)Cc;
        const float mur = wlds[0][tid] * invC, mui = wlds[1][tid] * invC;
        // V = E[x x^T] - mu mu^T + eps I
        const float a  = fmaf(-mur, mur, wlds[2][tid] * invC) + EPS_CLN;
        const float bb = fmaf(-mur, mui, wlds[3][tid] * invC);
        const float d  = fmaf(-mui, mui, wlds[4][tid] * invC) + EPS_CLN;
        // V^{-1/2} = [[d+s, -b],[-b, a+s]] / (s*tau);  s=sqrt(det), tau=sqrt(tr+2s)
        const float s   = sqrtf(fmaf(-bb, bb, a * d));
        const float tau = sqrtf(a + d + 2.0f * s);
        const float inv = 1.0f / (s * tau);
        wlds[0][tid] = mur;
        wlds[1][tid] = mui;
        wlds[2][tid] = (d + s) * inv;   // W00
        wlds[3][tid] = -bb * inv;       // W01 = W10
        wlds[4][tid] = (a + s) * inv;   // W11
    }
    __syncthreads();

    // ---- apply from registers; coalesced non-temporal float4 stores ----
    const float4 mur = *(const float4*)&wlds[0][tl];
    const float4 mui = *(const float4*)&wlds[1][tl];
    const float4 w00 = *(const float4*)&wlds[2][tl];
    const float4 w01 = *(const float4*)&wlds[3][tl];
    const float4 w11 = *(const float4*)&wlds[4][tl];

#pragma unroll
    for (int k = 0; k < CPT; ++k) {
        const int c = cbase + k;
        // weight layout (2,2,C): weight[i][j][c] -> wgt[(i*2+j)*C + c]
        const float wt00 = wgt[c];            // weight[0,0,c]
        const float wt01 = wgt[Cc + c];       // weight[0,1,c]
        const float wt10 = wgt[2 * Cc + c];   // weight[1,0,c]
        const float wt11 = wgt[3 * Cc + c];   // weight[1,1,c]
        const float b0 = bs[c];               // bias[0,c]
        const float b1 = bs[Cc + c];          // bias[1,c]
        float4 yr4, yi4;
#define APP1(cc) {                                         \
        float xcr = xr[k].cc - mur.cc;                     \
        float xci = xi[k].cc - mui.cc;                     \
        float zr = fmaf(xci, w01.cc, xcr * w00.cc);        \
        float zi = fmaf(xcr, w01.cc, xci * w11.cc);        \
        yr4.cc = fmaf(zr, wt00, fmaf(zi, wt10, b0));       \
        yi4.cc = fmaf(zr, wt01, fmaf(zi, wt11, b1)); }
        APP1(x) APP1(y) APP1(z) APP1(w)
#undef APP1
        // Non-temporal: outputs are never re-read -> don't pollute L2/L3,
        // keep the 134 MB input set resident in Infinity Cache across replays.
        __builtin_nontemporal_store(*(vfloat4*)&yr4, (vfloat4*)(yr_g + base + k * Tt));
        __builtin_nontemporal_store(*(vfloat4*)&yi4, (vfloat4*)(yi_g + base + k * Tt));
    }
}

extern "C" void kernel_launch(void* const* d_in, const int* in_sizes, int n_in,
                              void* d_out, int out_size, void* d_ws, size_t ws_size,
                              hipStream_t stream) {
    const float* xr  = (const float*)d_in[0];
    const float* xi  = (const float*)d_in[1];
    const float* wgt = (const float*)d_in[2];
    const float* bs  = (const float*)d_in[3];
    float* yr = (float*)d_out;
    float* yi = yr + (size_t)Bb * Cc * Tt;   // outputs concatenated flat
    dim3 grid(Bb * NTB);                     // 2048 blocks
    cln_kernel<<<grid, NTHR, 0, stream>>>(xr, xi, wgt, bs, yr, yi);
}

// Round 3
// 45.580 us; speedup vs baseline: 1.0887x; 1.0887x over previous
//
#include <hip/hip_runtime.h>
#include <math.h>

#define EPS_CLN 1e-6f

// Problem dims (fixed by the reference's setup_inputs)
constexpr int Bb = 8;
constexpr int Cc = 256;
constexpr int Tt = 8192;

// Tiling: one block = one b  x  TT consecutive t-values  x  all C channels.
// Thread = (channel-group cg of CPT channels) x (one float4 of t).
constexpr int TT   = 32;          // t-values per block
constexpr int CPT  = 8;           // channels per thread
constexpr int NCG  = Cc / CPT;    // 32 channel groups
constexpr int NT4  = TT / 4;      // 8 float4 slots along t
constexpr int NTHR = NCG * NT4;   // 256 threads
constexpr int NTB  = Tt / TT;     // 256 t-blocks per b

__global__ __launch_bounds__(NTHR, 4)
void cln_kernel(const float* __restrict__ xr_g, const float* __restrict__ xi_g,
                const float* __restrict__ wgt, const float* __restrict__ bs,
                float* __restrict__ yr_g, float* __restrict__ yi_g) {
    // Partial-sum scratch: [stat][channel-group][t]  (5*32*32*4 = 20 KB)
    __shared__ float red[5][NCG][TT];
    // Per-t params: raw sums -> then overwritten with mu_r, mu_i, W00, W01, W11
    __shared__ float wlds[5][TT];

    const int tid = threadIdx.x;
    const int t4i = tid & (NT4 - 1);   // which float4 along t
    const int cg  = tid >> 3;          // channel group (tid / NT4)
    const int tb  = blockIdx.x & (NTB - 1);
    const int b   = blockIdx.x >> 8;   // / NTB (=256)
    const int tl  = t4i * 4;           // local t of this thread's float4

    const int cbase = cg * CPT;
    const int base  = (b * Cc + cbase) * Tt + tb * TT + tl;

    // ---- single HBM read: 8 channels x 4 t x {re,im}, held in registers ----
    float4 xr[CPT], xi[CPT];
#pragma unroll
    for (int k = 0; k < CPT; ++k) {
        xr[k] = *(const float4*)(xr_g + base + k * Tt);
        xi[k] = *(const float4*)(xi_g + base + k * Tt);
    }

    // ---- per-thread partial stats over its 8 channels (componentwise per t) ----
    float4 sr = make_float4(0.f, 0.f, 0.f, 0.f);
    float4 si = sr, srr = sr, sri = sr, sii = sr;
#pragma unroll
    for (int k = 0; k < CPT; ++k) {
#define ACC1(c) { float r = xr[k].c, m = xi[k].c;          \
        sr.c += r; si.c += m;                              \
        srr.c = fmaf(r, r, srr.c);                         \
        sri.c = fmaf(r, m, sri.c);                         \
        sii.c = fmaf(m, m, sii.c); }
        ACC1(x) ACC1(y) ACC1(z) ACC1(w)
#undef ACC1
    }

    *(float4*)&red[0][cg][tl] = sr;
    *(float4*)&red[1][cg][tl] = si;
    *(float4*)&red[2][cg][tl] = srr;
    *(float4*)&red[3][cg][tl] = sri;
    *(float4*)&red[4][cg][tl] = sii;
    __syncthreads();

    // ---- parallel reduce over the 32 channel groups: 160 threads, one per (stat,t) ----
    if (tid < 5 * TT) {
        const int st = tid >> 5;       // stat 0..4
        const int t  = tid & (TT - 1); // t 0..31  -> bank = t, conflict-free
        float s = 0.f;
#pragma unroll
        for (int g = 0; g < NCG; ++g) s += red[st][g][t];
        wlds[st][t] = s;
    }
    __syncthreads();

    // ---- closed-form 2x2 inverse-sqrt whitening matrix, one thread per t ----
    if (tid < TT) {
        const float invC = 1.0f / (float)Cc;
        const float mur = wlds[0][tid] * invC, mui = wlds[1][tid] * invC;
        // V = E[x x^T] - mu mu^T + eps I
        const float a  = fmaf(-mur, mur, wlds[2][tid] * invC) + EPS_CLN;
        const float bb = fmaf(-mur, mui, wlds[3][tid] * invC);
        const float d  = fmaf(-mui, mui, wlds[4][tid] * invC) + EPS_CLN;
        // V^{-1/2} = [[d+s, -b],[-b, a+s]] / (s*tau);  s=sqrt(det), tau=sqrt(tr+2s)
        const float s   = sqrtf(fmaf(-bb, bb, a * d));
        const float tau = sqrtf(a + d + 2.0f * s);
        const float inv = 1.0f / (s * tau);
        wlds[0][tid] = mur;
        wlds[1][tid] = mui;
        wlds[2][tid] = (d + s) * inv;   // W00
        wlds[3][tid] = -bb * inv;       // W01 = W10
        wlds[4][tid] = (a + s) * inv;   // W11
    }
    __syncthreads();

    // ---- apply from registers; coalesced float4 stores (regular: L2 write-combines) ----
    const float4 mur = *(const float4*)&wlds[0][tl];
    const float4 mui = *(const float4*)&wlds[1][tl];
    const float4 w00 = *(const float4*)&wlds[2][tl];
    const float4 w01 = *(const float4*)&wlds[3][tl];
    const float4 w11 = *(const float4*)&wlds[4][tl];

#pragma unroll
    for (int k = 0; k < CPT; ++k) {
        const int c = cbase + k;
        // weight layout (2,2,C): weight[i][j][c] -> wgt[(i*2+j)*C + c]
        const float wt00 = wgt[c];            // weight[0,0,c]
        const float wt01 = wgt[Cc + c];       // weight[0,1,c]
        const float wt10 = wgt[2 * Cc + c];   // weight[1,0,c]
        const float wt11 = wgt[3 * Cc + c];   // weight[1,1,c]
        const float b0 = bs[c];               // bias[0,c]
        const float b1 = bs[Cc + c];          // bias[1,c]
        float4 yr4, yi4;
#define APP1(cc) {                                         \
        float xcr = xr[k].cc - mur.cc;                     \
        float xci = xi[k].cc - mui.cc;                     \
        float zr = fmaf(xci, w01.cc, xcr * w00.cc);        \
        float zi = fmaf(xcr, w01.cc, xci * w11.cc);        \
        yr4.cc = fmaf(zr, wt00, fmaf(zi, wt10, b0));       \
        yi4.cc = fmaf(zr, wt01, fmaf(zi, wt11, b1)); }
        APP1(x) APP1(y) APP1(z) APP1(w)
#undef APP1
        *(float4*)(yr_g + base + k * Tt) = yr4;
        *(float4*)(yi_g + base + k * Tt) = yi4;
    }
}

extern "C" void kernel_launch(void* const* d_in, const int* in_sizes, int n_in,
                              void* d_out, int out_size, void* d_ws, size_t ws_size,
                              hipStream_t stream) {
    const float* xr  = (const float*)d_in[0];
    const float* xi  = (const float*)d_in[1];
    const float* wgt = (const float*)d_in[2];
    const float* bs  = (const float*)d_in[3];
    float* yr = (float*)d_out;
    float* yi = yr + (size_t)Bb * Cc * Tt;   // outputs concatenated flat
    dim3 grid(Bb * NTB);                     // 2048 blocks
    cln_kernel<<<grid, NTHR, 0, stream>>>(xr, xi, wgt, bs, yr, yi);
}